// Round 2
// baseline (368.160 us; speedup 1.0000x reference)
//
#include <hip/hip_runtime.h>
#include <math.h>

#define N_NODES 50000
#define N_EDGES 400000
#define R_REL   35
#define B_BASES 12
#define C_DIM   128
#define HL_DIM  38
#define RI2     70            // R*2
#define NP      50304         // padded permuted node space (>= 50000 + 4*63, mult of 64)
#define WT_STRIDE 72          // wT row stride (16B-aligned rows)

// ---- ws float offsets ----
#define OFF_WT   0            // wT[128][72]
#define OFF_WQ   9216         // [70]
#define OFF_WK   9286         // [70]
#define OFF_LE   9356         // [2]
#define OFF_META 9360         // 12 ints: hist[4] @0, base_pad[4] @4, cursor[4] @8
#define OFF_PERM 9376         // int[50000]
#define OFF_INV  59376        // int[NP]
#define OFF_DEN  109680       // float[NP]       (contiguous with s_T for zeroing)
#define OFF_S    159984       // float[70][NP]
#define ZERO_F4  ((71 * NP) / 4)   // den + s_T = 892,896 float4
#define ZERO_BLOCKS 3488           // ceil(892896/256)

// K1: zero den+s_T, zero hist, compute wT[c][ri] = sum_b att_rel[r][b]*basis[b][i][c]
__global__ __launch_bounds__(256) void k_init(const float* __restrict__ basis,
                                              const float* __restrict__ att_rel,
                                              float* __restrict__ ws) {
    int b = blockIdx.x, tid = threadIdx.x;
    if (b < ZERO_BLOCKS) {
        int i = b * 256 + tid;
        if (i < ZERO_F4) ((float4*)(ws + OFF_DEN))[i] = make_float4(0.f, 0.f, 0.f, 0.f);
    } else if (b == ZERO_BLOCKS) {
        if (tid < 4) ((int*)(ws + OFF_META))[tid] = 0;
    } else {
        int idx = (b - (ZERO_BLOCKS + 1)) * 256 + tid;   // [0, 9216)
        int c = idx / WT_STRIDE;
        int ri = idx - c * WT_STRIDE;
        float acc = 0.f;
        if (ri < RI2) {
            int r = ri >> 1, ii = ri & 1;
            #pragma unroll
            for (int bb = 0; bb < B_BASES; ++bb)
                acc += att_rel[r * B_BASES + bb] * basis[(bb * 2 + ii) * C_DIM + c];
        }
        ws[OFF_WT + idx] = acc;
    }
}

// K2: type histogram (LDS-reduced)
__global__ __launch_bounds__(256) void k_hist(const int* __restrict__ node_type,
                                              float* __restrict__ ws) {
    __shared__ int lh[4];
    int tid = threadIdx.x;
    if (tid < 4) lh[tid] = 0;
    __syncthreads();
    int i = blockIdx.x * 256 + tid;
    if (i < N_NODES) atomicAdd(&lh[node_type[i]], 1);
    __syncthreads();
    if (tid < 4 && lh[tid] > 0) atomicAdd(&((int*)(ws + OFF_META))[tid], lh[tid]);
}

// K3: wq/wk/le projections + scan of histogram into 64-aligned base_pad, cursors=0
__global__ __launch_bounds__(256) void k_small(const float* __restrict__ q_att,
                                               const float* __restrict__ k_att,
                                               const float* __restrict__ e_att,
                                               const float* __restrict__ lin_edge_W,
                                               float* __restrict__ ws) {
    int tid = threadIdx.x;
    const float* wT = ws + OFF_WT;
    if (tid < RI2) {
        float a = 0.f;
        for (int c = 0; c < C_DIM; ++c) a += wT[c * WT_STRIDE + tid] * q_att[c];
        ws[OFF_WQ + tid] = a;
    } else if (tid < 2 * RI2) {
        int j = tid - RI2;
        float a = 0.f;
        for (int c = 0; c < C_DIM; ++c) a += wT[c * WT_STRIDE + j] * k_att[c];
        ws[OFF_WK + j] = a;
    } else if (tid == 140 || tid == 141) {
        int j = tid - 140;
        float a = 0.f;
        for (int c = 0; c < C_DIM; ++c) a += lin_edge_W[j * C_DIM + c] * e_att[c];
        ws[OFF_LE + j] = a;
    } else if (tid == 200) {
        int* meta = (int*)(ws + OFF_META);
        int h0 = meta[0], h1 = meta[1], h2 = meta[2];
        int b1 = ((h0 + 63) >> 6) << 6;
        int b2 = b1 + (((h1 + 63) >> 6) << 6);
        int b3 = b2 + (((h2 + 63) >> 6) << 6);
        meta[4] = 0; meta[5] = b1; meta[6] = b2; meta[7] = b3;
        meta[8] = 0; meta[9] = 0; meta[10] = 0; meta[11] = 0;
    }
}

// K4: counting-sort scatter: perm[n] = base_pad[t] + rank (wave-aggregated atomics)
__global__ __launch_bounds__(64) void k_perm(const int* __restrict__ node_type,
                                             float* __restrict__ ws) {
    int lane = threadIdx.x;
    int n = blockIdx.x * 64 + lane;
    int* meta = (int*)(ws + OFF_META);
    int* perm = (int*)(ws + OFF_PERM);
    int* inv  = (int*)(ws + OFF_INV);
    bool active = n < N_NODES;
    int ty = active ? node_type[n] : -1;
    for (int t = 0; t < 4; ++t) {
        bool mine = active && (ty == t);
        unsigned long long m = __ballot(mine);
        if (m == 0ULL) continue;
        int leader = __ffsll(m) - 1;
        int base = 0;
        if (lane == leader) base = atomicAdd(&meta[8 + t], __popcll(m));
        base = __shfl(base, leader);
        if (mine) {
            int p = meta[4 + t] + base + __popcll(m & ((1ULL << lane) - 1ULL));
            perm[n] = p;
            inv[p] = n;
        }
    }
}

// K5: edge pass -> 3 atomics into permuted space
__global__ __launch_bounds__(256) void k_edge(const float* __restrict__ x,
                                              const int* __restrict__ edge_index,
                                              const int* __restrict__ edge_type,
                                              const float* __restrict__ edge_attr,
                                              float* __restrict__ ws) {
    __shared__ float swq[RI2], swk[RI2], sle[2];
    int tid = threadIdx.x;
    if (tid < RI2) { swq[tid] = ws[OFF_WQ + tid]; swk[tid] = ws[OFF_WK + tid]; }
    if (tid < 2) sle[tid] = ws[OFF_LE + tid];
    __syncthreads();
    int e = blockIdx.x * 256 + tid;
    if (e >= N_EDGES) return;
    int src = edge_index[e];
    int dst = edge_index[N_EDGES + e];
    int r   = edge_type[e];
    int p   = ((const int*)(ws + OFF_PERM))[dst];
    float2 ea = *(const float2*)(edge_attr + 2 * e);
    float2 xs = *(const float2*)(x + 2 * src);
    float2 xd = *(const float2*)(x + 2 * dst);
    float alpha = xd.x * swq[2 * r] + xd.y * swq[2 * r + 1]
                + xs.x * swk[2 * r] + xs.y * swk[2 * r + 1]
                + ea.x * sle[0]     + ea.y * sle[1];
    alpha = alpha > 0.f ? alpha : 0.2f * alpha;
    float ex = __expf(alpha);
    atomicAdd(ws + OFF_DEN + p, ex);
    atomicAdd(ws + OFF_S + (2 * r) * NP + p,     ex * xs.x);
    atomicAdd(ws + OFF_S + (2 * r + 1) * NP + p, ex * xs.y);
}

// K6: fused node pass, thread-per-node, type-uniform blocks -> SGPR weight streams
__global__ __launch_bounds__(64) void k_node(
        const float* __restrict__ ws, const float* __restrict__ conv_bias,
        const float* __restrict__ lin0_W, const float* __restrict__ lin0_b,
        const float* __restrict__ lin1_W, const float* __restrict__ lin1_b,
        const float* __restrict__ lin2_W, const float* __restrict__ lin2_b,
        const float* __restrict__ fin_W,  const float* __restrict__ fin_b,
        float* __restrict__ out) {
    __shared__ float yA[HL_DIM * 64];
    __shared__ float yB[HL_DIM * 64];
    int lane = threadIdx.x;
    int p0 = blockIdx.x * 64;
    int p  = p0 + lane;
    const int* meta = (const int*)(ws + OFF_META);
    int b1 = __builtin_amdgcn_readfirstlane(meta[5]);
    int b2 = __builtin_amdgcn_readfirstlane(meta[6]);
    int b3 = __builtin_amdgcn_readfirstlane(meta[7]);
    int t  = (p0 >= b1) + (p0 >= b2) + (p0 >= b3);   // block-uniform (bases 64-aligned)
    int bp = t == 0 ? 0 : (t == 1 ? b1 : (t == 2 ? b2 : b3));
    int cnt = __builtin_amdgcn_readfirstlane(meta[t]);
    bool valid = (p - bp) < cnt;
    int orig = valid ? ((const int*)(ws + OFF_INV))[p] : 0;

    // coalesced per-lane loads of s row + den
    const float* sT = ws + OFF_S;
    float s[RI2];
    #pragma unroll
    for (int ri = 0; ri < RI2; ++ri) s[ri] = sT[ri * NP + p];
    float inv_dn = 1.0f / (ws[OFF_DEN + p] + 1e-16f);

    // fused agg + lin0: h[c] never materialized
    const float* wT = ws + OFF_WT;
    const float* W0 = lin0_W + t * C_DIM * HL_DIM;
    float y0[HL_DIM];
    #pragma unroll
    for (int j = 0; j < HL_DIM; ++j) y0[j] = lin0_b[t * HL_DIM + j];
    for (int c = 0; c < C_DIM; ++c) {
        const float* wr = wT + c * WT_STRIDE;      // scalar (SGPR) stream
        float acc = 0.f;
        #pragma unroll
        for (int ri = 0; ri < RI2; ++ri) acc += s[ri] * wr[ri];
        float hc = acc * inv_dn + conv_bias[c];
        hc = hc > 0.f ? hc : 0.f;                  // relu(leaky_relu(x)) == relu(x)
        const float* w0r = W0 + c * HL_DIM;        // scalar stream
        #pragma unroll
        for (int j = 0; j < HL_DIM; ++j) y0[j] += hc * w0r[j];
    }
    #pragma unroll
    for (int j = 0; j < HL_DIM; ++j) yA[j * 64 + lane] = y0[j] > 0.f ? y0[j] : 0.f;

    const float* W1 = lin1_W + t * HL_DIM * HL_DIM;
    float y1[HL_DIM];
    #pragma unroll
    for (int j = 0; j < HL_DIM; ++j) y1[j] = lin1_b[t * HL_DIM + j];
    for (int k = 0; k < HL_DIM; ++k) {
        float v = yA[k * 64 + lane];               // own-lane LDS, no barrier needed
        const float* w1r = W1 + k * HL_DIM;
        #pragma unroll
        for (int j = 0; j < HL_DIM; ++j) y1[j] += v * w1r[j];
    }
    #pragma unroll
    for (int j = 0; j < HL_DIM; ++j) yB[j * 64 + lane] = y1[j] > 0.f ? y1[j] : 0.f;

    const float* W2 = lin2_W + t * HL_DIM * HL_DIM;
    float y2[HL_DIM];
    #pragma unroll
    for (int j = 0; j < HL_DIM; ++j) y2[j] = lin2_b[t * HL_DIM + j];
    for (int k = 0; k < HL_DIM; ++k) {
        float v = yB[k * 64 + lane];
        const float* w2r = W2 + k * HL_DIM;
        #pragma unroll
        for (int j = 0; j < HL_DIM; ++j) y2[j] += v * w2r[j];
    }
    #pragma unroll
    for (int j = 0; j < HL_DIM; ++j) yA[j * 64 + lane] = y2[j];   // raw (no relu)

    const float* FW = fin_W + t * HL_DIM * 2;
    float o0 = fin_b[t * 2], o1 = fin_b[t * 2 + 1];
    for (int k = 0; k < HL_DIM; ++k) {
        float v = yA[k * 64 + lane];
        o0 += v * FW[k * 2];
        o1 += v * FW[k * 2 + 1];
    }
    if (t == 0) o1 = fabsf(o1);
    if (valid) ((float2*)out)[orig] = make_float2(o0, o1);
}

extern "C" void kernel_launch(void* const* d_in, const int* in_sizes, int n_in,
                              void* d_out, int out_size, void* d_ws, size_t ws_size,
                              hipStream_t stream) {
    const float* x          = (const float*)d_in[0];
    const int*   edge_index = (const int*)  d_in[1];
    const int*   edge_type  = (const int*)  d_in[2];
    const float* edge_attr  = (const float*)d_in[3];
    const int*   node_type  = (const int*)  d_in[4];
    const float* basis      = (const float*)d_in[5];
    const float* att_rel    = (const float*)d_in[6];
    const float* q_att      = (const float*)d_in[7];
    const float* k_att      = (const float*)d_in[8];
    const float* e_att      = (const float*)d_in[9];
    const float* lin_edge_W = (const float*)d_in[10];
    const float* conv_bias  = (const float*)d_in[11];
    const float* lin0_W     = (const float*)d_in[12];
    const float* lin0_b     = (const float*)d_in[13];
    const float* lin1_W     = (const float*)d_in[14];
    const float* lin1_b     = (const float*)d_in[15];
    const float* lin2_W     = (const float*)d_in[16];
    const float* lin2_b     = (const float*)d_in[17];
    const float* fin_W      = (const float*)d_in[18];
    const float* fin_b      = (const float*)d_in[19];

    float* ws  = (float*)d_ws;
    float* out = (float*)d_out;

    k_init <<<ZERO_BLOCKS + 1 + 36, 256, 0, stream>>>(basis, att_rel, ws);
    k_hist <<<(N_NODES + 255) / 256, 256, 0, stream>>>(node_type, ws);
    k_small<<<1, 256, 0, stream>>>(q_att, k_att, e_att, lin_edge_W, ws);
    k_perm <<<(N_NODES + 63) / 64, 64, 0, stream>>>(node_type, ws);
    k_edge <<<(N_EDGES + 255) / 256, 256, 0, stream>>>(x, edge_index, edge_type, edge_attr, ws);
    k_node <<<NP / 64, 64, 0, stream>>>(ws, conv_bias,
                                        lin0_W, lin0_b, lin1_W, lin1_b,
                                        lin2_W, lin2_b, fin_W, fin_b, out);
}